// Round 6
// baseline (2789.286 us; speedup 1.0000x reference)
//
#include <hip/hip_runtime.h>
#include <math.h>

#define TLEN 1022
#define SLEN 1024
#define NB   64
#define NE   256
#define NF   256
#define NH   256
#define NG   1024
#define TC   256      // chunk length (last chunk = 254)

typedef _Float16 h2_t __attribute__((ext_vector_type(2)));

#if defined(__has_builtin)
# if __has_builtin(__builtin_amdgcn_fdot2)
#  define HAVE_FDOT2 1
# endif
#endif
#ifndef HAVE_FDOT2
# define HAVE_FDOT2 0
#endif

__device__ __forceinline__ float sigm(float x){ return 1.f/(1.f+__expf(-x)); }
__device__ __forceinline__ float tanh_(float x){ return 1.f - 2.f/(__expf(2.f*x)+1.f); }

__device__ __forceinline__ unsigned int packh2(float x, float y){
  h2_t p; p.x = (_Float16)x; p.y = (_Float16)y;
  return __builtin_bit_cast(unsigned int, p);
}
__device__ __forceinline__ float dot2_acc(unsigned int w, unsigned int h, float acc){
  h2_t a = __builtin_bit_cast(h2_t, w);
  h2_t b = __builtin_bit_cast(h2_t, h);
#if HAVE_FDOT2
  return __builtin_amdgcn_fdot2(a, b, acc, false);
#else
  return acc + (float)a.x*(float)b.x + (float)a.y*(float)b.y;
#endif
}

// bias4[g] = b_ih[g] + b_hh[g] + sum_f conv_b[f]*w_ih[g][f]
__global__ __launch_bounds__(256) void k_bias(const float* __restrict__ conv_b,
                                              const float* __restrict__ w_ih,
                                              const float* __restrict__ b_ih,
                                              const float* __restrict__ b_hh,
                                              float* __restrict__ bias4){
  int g = blockIdx.x*256 + threadIdx.x;
  const float* row = w_ih + (size_t)g*NF;
  float s = b_ih[g] + b_hh[g];
  for (int f=0; f<NF; f+=4){
    float4 w4 = *(const float4*)(row+f);
    float4 c4 = *(const float4*)(conv_b+f);
    s += w4.x*c4.x + w4.y*c4.y + w4.z*c4.z + w4.w*c4.w;
  }
  bias4[g] = s;
}

// Prepack w_hh (fp32 [1024][256]) into per-thread f16-pair layout for 1024-thread k_rnn:
// pall4[cp][tid], cp<32, tid<1024. Thread tid=(wv*64+l): kq=wv>>2, jq=wv&3.
// uint4 element e = row jq*256 + l*4 + e, cols kq*64 + 2cp, +1.
__global__ __launch_bounds__(256) void k_pack(const float* __restrict__ w_hh,
                                              uint4* __restrict__ pall4){
  int gid = blockIdx.x*256 + threadIdx.x;     // 0..32767
  int tid = gid & 1023, cp = gid >> 10;
  int l = tid & 63, wv = tid >> 6, kq = wv >> 2, jq = wv & 3;
  unsigned int c[4];
  #pragma unroll
  for (int e=0;e<4;++e){
    int row = jq*256 + l*4 + e, col = kq*64 + 2*cp;
    const float* p = w_hh + (size_t)row*NH + col;
    c[e] = packh2(p[0], p[1]);
  }
  pall4[(size_t)cp*1024 + tid] = make_uint4(c[0],c[1],c[2],c[3]);
}

// conv chunk: conv[(tl*64+b)*256+f] for tl in [0,TC), t = t0+tl
#define CTT 32
__global__ __launch_bounds__(256) void k_conv(const int* __restrict__ ipts,
                                              const float* __restrict__ emb,
                                              const float* __restrict__ conv_w,
                                              float* __restrict__ conv, int t0){
  __shared__ float embl[CTT+2][257];
  __shared__ float wl[16*256];
  const int b    = blockIdx.y;
  const int tl0  = blockIdx.x*CTT;
  const int tg0  = t0 + tl0;
  const int tid  = threadIdx.x;

  for (int i=tid; i<(CTT+2)*64; i+=256){
    int row = i>>6, c4 = (i&63)<<2;
    int s = tg0 + row;
    int tok = (s < SLEN) ? ipts[b*SLEN + s] : 0;
    float4 v = *(const float4*)(emb + (size_t)tok*NE + c4);
    embl[row][c4+0]=v.x; embl[row][c4+1]=v.y; embl[row][c4+2]=v.z; embl[row][c4+3]=v.w;
  }

  const int tt4 = tid>>6;
  const int f4  = (tid&63)<<2;
  float acc[8][4];
  #pragma unroll
  for (int i=0;i<8;++i){ acc[i][0]=0.f; acc[i][1]=0.f; acc[i][2]=0.f; acc[i][3]=0.f; }

  for (int k0=0; k0<768; k0+=16){
    __syncthreads();
    for (int i=tid; i<1024; i+=256){
      float4 v = *(const float4*)(conv_w + (size_t)k0*NF + 4*(size_t)i);
      *(((float4*)wl)+i) = v;
    }
    __syncthreads();
    const int w = k0>>8, e0 = k0&255;
    #pragma unroll
    for (int kk=0; kk<16; ++kk){
      float a[8];
      #pragma unroll
      for (int i=0;i<8;++i) a[i] = embl[tt4*8 + i + w][e0 + kk];
      float4 wv = *(const float4*)(wl + kk*NF + f4);
      #pragma unroll
      for (int i=0;i<8;++i){
        acc[i][0] += a[i]*wv.x; acc[i][1] += a[i]*wv.y;
        acc[i][2] += a[i]*wv.z; acc[i][3] += a[i]*wv.w;
      }
    }
  }
  #pragma unroll
  for (int i=0;i<8;++i){
    int tl = tl0 + tt4*8 + i;
    if (t0 + tl < TLEN){
      float4 v = make_float4(acc[i][0],acc[i][1],acc[i][2],acc[i][3]);
      *(float4*)(conv + ((size_t)tl*NB + b)*NF + f4) = v;
    }
  }
}

// xg chunk (f16 out): xh[(tl*64+b)*1024+g] = conv[r][:] . w_ih[g][:] + bias4[g]
__global__ __launch_bounds__(256) void k_xg(const float* __restrict__ conv,
                                            const float* __restrict__ w_ih,
                                            const float* __restrict__ bias4,
                                            unsigned short* __restrict__ xh){
  __shared__ float al[64][17];
  __shared__ float bl[16][64];
  const int g0  = blockIdx.x*64;
  const int m0  = blockIdx.y*64;
  const int tid = threadIdx.x;
  const int ty  = tid>>4, tx = tid&15;
  const int rr  = tid>>2, kq = (tid&3)<<2;
  float acc[4][4];
  #pragma unroll
  for (int i=0;i<4;++i){ acc[i][0]=0.f; acc[i][1]=0.f; acc[i][2]=0.f; acc[i][3]=0.f; }

  for (int k0=0; k0<256; k0+=16){
    __syncthreads();
    {
      float4 v = *(const float4*)(conv + (size_t)(m0+rr)*NF + k0 + kq);
      al[rr][kq+0]=v.x; al[rr][kq+1]=v.y; al[rr][kq+2]=v.z; al[rr][kq+3]=v.w;
      float4 u = *(const float4*)(w_ih + (size_t)(g0+rr)*NF + k0 + kq);
      bl[kq+0][rr]=u.x; bl[kq+1][rr]=u.y; bl[kq+2][rr]=u.z; bl[kq+3][rr]=u.w;
    }
    __syncthreads();
    #pragma unroll
    for (int kk=0; kk<16; ++kk){
      float a0=al[ty*4+0][kk], a1=al[ty*4+1][kk], a2=al[ty*4+2][kk], a3=al[ty*4+3][kk];
      float4 bv = *(const float4*)&bl[kk][tx*4];
      acc[0][0]+=a0*bv.x; acc[0][1]+=a0*bv.y; acc[0][2]+=a0*bv.z; acc[0][3]+=a0*bv.w;
      acc[1][0]+=a1*bv.x; acc[1][1]+=a1*bv.y; acc[1][2]+=a1*bv.z; acc[1][3]+=a1*bv.w;
      acc[2][0]+=a2*bv.x; acc[2][1]+=a2*bv.y; acc[2][2]+=a2*bv.z; acc[2][3]+=a2*bv.w;
      acc[3][0]+=a3*bv.x; acc[3][1]+=a3*bv.y; acc[3][2]+=a3*bv.z; acc[3][3]+=a3*bv.w;
    }
  }
  float4 bb = *(const float4*)(bias4 + g0 + tx*4);
  #pragma unroll
  for (int i=0;i<4;++i){
    size_t r = (size_t)m0 + ty*4 + i;
    unsigned int p0 = packh2(acc[i][0]+bb.x, acc[i][1]+bb.y);
    unsigned int p1 = packh2(acc[i][2]+bb.z, acc[i][3]+bb.w);
    *(uint2*)(xh + r*NG + g0 + tx*4) = make_uint2(p0, p1);
  }
}

// LSTM chunk. 64 WGs (one per batch) x 1024 threads (16 waves, 4/SIMD).
// wave wv: kq=wv>>2 (k-slice of 64 cols = 32 pairs), jq=wv&3 (row quarter).
// thread l: rows jq*256 + 4l + r (r<4). Per-thread 128 pairs:
//   cp in [0,8)  -> LDS wlds4[8][1024] (128 KB), staged once
//   cp in [8,32) -> 96 VGPRs (demand ~116 < the 128-reg budget at 4 waves/EU,
//                   so the allocator has no reason to spill or rematerialize)
// Zero per-step global weight traffic.
__global__ __attribute__((amdgpu_flat_work_group_size(1024,1024)))
__attribute__((amdgpu_waves_per_eu(4,4)))
void k_rnn(const unsigned short* __restrict__ xh,
           const uint4* __restrict__ pall4,
           const float* __restrict__ h0,
           const float* __restrict__ c0,
           const int* __restrict__ seqlen,
           const float* __restrict__ lin_w,
           const float* __restrict__ lin_b,
           unsigned int* __restrict__ h_ws,
           float* __restrict__ c_ws,
           float* __restrict__ ms_ws,
           float* __restrict__ out,
           int t0, int tcount, int is_first, int is_last){
  __shared__ uint4 wlds4[8][1024];          // 128 KB: weight pairs for cp in [0,8)
  __shared__ float part[4][1024];           // 16 KB: per-kq partial gate sums
  __shared__ unsigned int hp[128];          // h as f16 pairs
  __shared__ float red[256];
  const int b   = blockIdx.x;
  const int tid = threadIdx.x;
  const int l   = tid & 63, wv = tid >> 6;
  const int kq  = wv >> 2, jq = wv & 3;
  const int jbase = jq*256 + 4*l;

  // stage LDS-resident weights (cp = 0..7)
  #pragma unroll
  for (int cp=0; cp<8; ++cp)
    wlds4[cp][tid] = pall4[(size_t)cp*1024 + tid];

  // register-resident weights (cp = 8..31): wreg[(cp-8)*4 + r]
  unsigned int wreg[96];
  #pragma unroll
  for (int cp=8; cp<32; ++cp){
    uint4 v = pall4[(size_t)cp*1024 + tid];
    wreg[4*(cp-8)+0]=v.x; wreg[4*(cp-8)+1]=v.y; wreg[4*(cp-8)+2]=v.z; wreg[4*(cp-8)+3]=v.w;
  }
  #pragma unroll
  for (int i=0;i<96;++i) asm volatile("" : "+v"(wreg[i]));

  float creg = 0.f, msum = 0.f;
  if (is_first){
    if (tid < 128) hp[tid] = packh2(h0[(size_t)b*NH + 2*tid], h0[(size_t)b*NH + 2*tid + 1]);
    if (tid < 256) creg = c0[(size_t)b*NH + tid];
  } else {
    if (tid < 128) hp[tid] = h_ws[b*128 + tid];
    if (tid < 256){ creg = c_ws[b*256 + tid]; msum = ms_ws[b*256 + tid]; }
  }
  const int L = seqlen[b];
  __syncthreads();

  const unsigned short* xrow = xh + (size_t)b*NG + tid;

  for (int tl=0; tl<tcount; ++tl){
    // ---- prefetch xg for this step (raw; converted after barrier) ----
    unsigned short xr0=0, xr1=0, xr2=0, xr3=0;
    if (tid < 256){
      const unsigned short* xr = xrow + (size_t)tl*NB*NG;
      xr0 = xr[0]; xr1 = xr[256]; xr2 = xr[512]; xr3 = xr[768];
    }

    float pa[4] = {0.f, 0.f, 0.f, 0.f};

    // MAC over cp = 0..31; h pairs read 4-at-a-time as b128 (wave-uniform addr)
    #pragma unroll
    for (int c=0; c<8; ++c){
      uint4 hv = *(const uint4*)&hp[kq*32 + 4*c];
      unsigned int hvv[4] = {hv.x, hv.y, hv.z, hv.w};
      #pragma unroll
      for (int e=0; e<4; ++e){
        const int cp = 4*c + e;
        uint4 wv4;
        if (cp < 8) wv4 = wlds4[cp][tid];
        else        wv4 = make_uint4(wreg[4*(cp-8)+0], wreg[4*(cp-8)+1],
                                     wreg[4*(cp-8)+2], wreg[4*(cp-8)+3]);
        pa[0] = dot2_acc(wv4.x, hvv[e], pa[0]);
        pa[1] = dot2_acc(wv4.y, hvv[e], pa[1]);
        pa[2] = dot2_acc(wv4.z, hvv[e], pa[2]);
        pa[3] = dot2_acc(wv4.w, hvv[e], pa[3]);
      }
    }

    *(float4*)&part[kq][jbase] = make_float4(pa[0],pa[1],pa[2],pa[3]);
    __syncthreads();

    if (tid < 256){
      unsigned short xr4[4] = {xr0, xr1, xr2, xr3};
      float a[4];
      #pragma unroll
      for (int q=0;q<4;++q){
        int G = q*256 + tid;
        float s = (float)__builtin_bit_cast(_Float16, xr4[q]);
        #pragma unroll
        for (int k=0;k<4;++k) s += part[k][G];
        a[q] = s;
      }
      float si = sigm(a[0]), sf = sigm(a[1]), so = sigm(a[3]);
      float tg = tanh_(a[2]);
      creg = sf*creg + si*tg;
      float h2 = so*tanh_(creg);
      if (t0 + tl < L) msum += h2;
      ((_Float16*)hp)[tid] = (_Float16)h2;
    }
    __syncthreads();
  }

  if (tid < 128) h_ws[b*128 + tid] = hp[tid];
  if (tid < 256){ c_ws[b*256 + tid] = creg; ms_ws[b*256 + tid] = msum; }

  if (is_last){
    if (tid < 256) red[tid] = (msum / (float)L) * lin_w[tid];
    __syncthreads();
    if (tid < 64){
      float s = red[tid] + red[tid+64] + red[tid+128] + red[tid+192];
      #pragma unroll
      for (int off=32; off>0; off>>=1) s += __shfl_down(s, off);
      if (tid==0) out[b] = sigm(s + lin_b[0]);
    }
  }
}

extern "C" void kernel_launch(void* const* d_in, const int* in_sizes, int n_in,
                              void* d_out, int out_size, void* d_ws, size_t ws_size,
                              hipStream_t stream){
  const int*   ipts   = (const int*)d_in[0];
  const int*   seqlen = (const int*)d_in[1];
  const float* h0     = (const float*)d_in[2];
  const float* c0     = (const float*)d_in[3];
  const float* emb    = (const float*)d_in[4];
  const float* conv_w = (const float*)d_in[5];
  const float* conv_b = (const float*)d_in[6];
  const float* w_ih   = (const float*)d_in[7];
  const float* w_hh   = (const float*)d_in[8];
  const float* b_ih   = (const float*)d_in[9];
  const float* b_hh   = (const float*)d_in[10];
  const float* lin_w  = (const float*)d_in[11];
  const float* lin_b  = (const float*)d_in[12];
  float* out = (float*)d_out;

  char* ws = (char*)d_ws;
  const size_t XH_B   = (size_t)TC*NB*NG*2;      // 33.5 MB
  const size_t CONV_B = (size_t)TC*NB*NF*4;      // 16.8 MB
  const size_t PALL_B = (size_t)32*1024*16;      // 512 KB
  unsigned short* xh    = (unsigned short*)ws;
  float*          convc = (float*)(ws + XH_B);
  uint4*          pall4 = (uint4*)(ws + XH_B + CONV_B);
  float*          bias4 = (float*)(ws + XH_B + CONV_B + PALL_B);
  unsigned int*   h_ws  = (unsigned int*)(ws + XH_B + CONV_B + PALL_B + 4096);
  float*          c_ws  = (float*)(ws + XH_B + CONV_B + PALL_B + 4096 + 32768);
  float*          ms_ws = (float*)(ws + XH_B + CONV_B + PALL_B + 4096 + 32768 + 65536);

  k_bias<<<dim3(4),   dim3(256), 0, stream>>>(conv_b, w_ih, b_ih, b_hh, bias4);
  k_pack<<<dim3(128), dim3(256), 0, stream>>>(w_hh, pall4);

  for (int t0 = 0; t0 < TLEN; t0 += TC){
    int tcount = (TLEN - t0 < TC) ? (TLEN - t0) : TC;
    int is_first = (t0 == 0), is_last = (t0 + TC >= TLEN);
    k_conv<<<dim3(TC/CTT, NB), dim3(256), 0, stream>>>(ipts, emb, conv_w, convc, t0);
    k_xg  <<<dim3(16, TC),     dim3(256), 0, stream>>>(convc, w_ih, bias4, xh);
    k_rnn <<<dim3(NB),         dim3(1024), 0, stream>>>(xh, pall4, h0, c0, seqlen,
                                                        lin_w, lin_b, h_ws, c_ws, ms_ws, out,
                                                        t0, tcount, is_first, is_last);
  }
}

// Round 7
// 1762.269 us; speedup vs baseline: 1.5828x; 1.5828x over previous
//
#include <hip/hip_runtime.h>
#include <hip/hip_bf16.h>
#include <math.h>

#define TLEN 1022
#define SLEN 1024
#define NB   64
#define NE   256
#define NF   256
#define NH   256
#define NG   1024
#define TC   256      // chunk length (last chunk = 254)

typedef _Float16 h2_t __attribute__((ext_vector_type(2)));
typedef __attribute__((ext_vector_type(8))) short bf16x8;
typedef __attribute__((ext_vector_type(4))) float f32x4;

#if defined(__has_builtin)
# if __has_builtin(__builtin_amdgcn_fdot2)
#  define HAVE_FDOT2 1
# endif
#endif
#ifndef HAVE_FDOT2
# define HAVE_FDOT2 0
#endif

__device__ __forceinline__ float sigm(float x){ return 1.f/(1.f+__expf(-x)); }
__device__ __forceinline__ float tanh_(float x){ return 1.f - 2.f/(__expf(2.f*x)+1.f); }

__device__ __forceinline__ unsigned int packh2(float x, float y){
  h2_t p; p.x = (_Float16)x; p.y = (_Float16)y;
  return __builtin_bit_cast(unsigned int, p);
}
__device__ __forceinline__ float dot2_acc(unsigned int w, unsigned int h, float acc){
  h2_t a = __builtin_bit_cast(h2_t, w);
  h2_t b = __builtin_bit_cast(h2_t, h);
#if HAVE_FDOT2
  return __builtin_amdgcn_fdot2(a, b, acc, false);
#else
  return acc + (float)a.x*(float)b.x + (float)a.y*(float)b.y;
#endif
}
__device__ __forceinline__ unsigned short f2bf(float x){
  __hip_bfloat16 b = __float2bfloat16(x);
  return __builtin_bit_cast(unsigned short, b);
}

// bias4[g] = b_ih[g] + b_hh[g] + sum_f conv_b[f]*w_ih[g][f]
__global__ __launch_bounds__(256) void k_bias(const float* __restrict__ conv_b,
                                              const float* __restrict__ w_ih,
                                              const float* __restrict__ b_ih,
                                              const float* __restrict__ b_hh,
                                              float* __restrict__ bias4){
  int g = blockIdx.x*256 + threadIdx.x;
  const float* row = w_ih + (size_t)g*NF;
  float s = b_ih[g] + b_hh[g];
  for (int f=0; f<NF; f+=4){
    float4 w4 = *(const float4*)(row+f);
    float4 c4 = *(const float4*)(conv_b+f);
    s += w4.x*c4.x + w4.y*c4.y + w4.z*c4.z + w4.w*c4.w;
  }
  bias4[g] = s;
}

// Prepack w_hh (fp32 [1024][256]) into per-thread f16-pair layout (512-thread k_rnn):
// pall4[j][tid], j<64, tid<512. Thread tid=(wv*64+l): kq=wv>>1, jh=wv&1.
// pair idx = 4j+e, cp = idx>>3 (0..31), r = idx&7; row = jh*512 + l*8 + r;
// cols = kq*64 + 2cp, +1.
__global__ __launch_bounds__(256) void k_pack(const float* __restrict__ w_hh,
                                              uint4* __restrict__ pall4){
  int gid = blockIdx.x*256 + threadIdx.x;     // 0..32767
  int tid = gid & 511, j = gid >> 9;
  int l = tid & 63, wv = tid >> 6, kq = wv >> 1, jh = wv & 1;
  unsigned int c[4];
  #pragma unroll
  for (int e=0;e<4;++e){
    int idx = 4*j + e, cp = idx >> 3, r = idx & 7;
    int row = jh*512 + l*8 + r, col = kq*64 + 2*cp;
    const float* p = w_hh + (size_t)row*NH + col;
    c[e] = packh2(p[0], p[1]);
  }
  pall4[(size_t)j*512 + tid] = make_uint4(c[0],c[1],c[2],c[3]);
}

// CW2T[g][k] = sum_f w_ih[g][f] * conv_w_flat[k][f]   (M=1024 g, N=768 k, K=256 f)
// bf16 output, row-major [1024][768].
__global__ __launch_bounds__(256) void k_cw2(const float* __restrict__ w_ih,
                                             const float* __restrict__ conv_w,
                                             unsigned short* __restrict__ cw2t){
  __shared__ float al[64][17];
  __shared__ float bl[16][64];
  const int n0  = blockIdx.x*64;   // k-dim (768)
  const int m0  = blockIdx.y*64;   // g-dim (1024)
  const int tid = threadIdx.x;
  const int ty  = tid>>4, tx = tid&15;
  const int rr  = tid>>2, kq = (tid&3)<<2;
  float acc[4][4];
  #pragma unroll
  for (int i=0;i<4;++i){ acc[i][0]=0.f; acc[i][1]=0.f; acc[i][2]=0.f; acc[i][3]=0.f; }

  for (int k0=0; k0<256; k0+=16){
    __syncthreads();
    {
      float4 v = *(const float4*)(w_ih + (size_t)(m0+rr)*NF + k0 + kq);
      al[rr][kq+0]=v.x; al[rr][kq+1]=v.y; al[rr][kq+2]=v.z; al[rr][kq+3]=v.w;
      float4 u = *(const float4*)(conv_w + (size_t)(n0+rr)*NF + k0 + kq);
      bl[kq+0][rr]=u.x; bl[kq+1][rr]=u.y; bl[kq+2][rr]=u.z; bl[kq+3][rr]=u.w;
    }
    __syncthreads();
    #pragma unroll
    for (int kk=0; kk<16; ++kk){
      float a0=al[ty*4+0][kk], a1=al[ty*4+1][kk], a2=al[ty*4+2][kk], a3=al[ty*4+3][kk];
      float4 bv = *(const float4*)&bl[kk][tx*4];
      acc[0][0]+=a0*bv.x; acc[0][1]+=a0*bv.y; acc[0][2]+=a0*bv.z; acc[0][3]+=a0*bv.w;
      acc[1][0]+=a1*bv.x; acc[1][1]+=a1*bv.y; acc[1][2]+=a1*bv.z; acc[1][3]+=a1*bv.w;
      acc[2][0]+=a2*bv.x; acc[2][1]+=a2*bv.y; acc[2][2]+=a2*bv.z; acc[2][3]+=a2*bv.w;
      acc[3][0]+=a3*bv.x; acc[3][1]+=a3*bv.y; acc[3][2]+=a3*bv.z; acc[3][3]+=a3*bv.w;
    }
  }
  #pragma unroll
  for (int i=0;i<4;++i){
    size_t r = (size_t)m0 + ty*4 + i;
    unsigned int p0 = (unsigned int)f2bf(acc[i][0]) | ((unsigned int)f2bf(acc[i][1])<<16);
    unsigned int p1 = (unsigned int)f2bf(acc[i][2]) | ((unsigned int)f2bf(acc[i][3])<<16);
    *(uint2*)(cw2t + r*768 + n0 + tx*4) = make_uint2(p0, p1);
  }
}

// Fused conv+xg GEMM: xh[m][g] = f16( sum_k A[m][k]*CW2T[g][k] + bias4[g] )
// A[m][k] = emb[ tok(b, t0+tl+w) ][e],  m=(tl*64+b), k=w*256+e.  M=16384, K=768, N=1024.
// Tile 128(m) x 256(n), BK=64. 4 waves, each 64x128 (acc[4][8]).
__global__ __launch_bounds__(256,2) void k_fxg(const int* __restrict__ ipts,
                                               const float* __restrict__ emb,
                                               const unsigned short* __restrict__ cw2t,
                                               const float* __restrict__ bias4,
                                               unsigned short* __restrict__ xh,
                                               int t0){
  __shared__ unsigned short A_l[128][72];   // [m][k] bf16, pad 72
  __shared__ unsigned short B_l[256][72];   // [n][k] bf16, pad 72
  __shared__ int tokl[4][64];
  const int tid = threadIdx.x;
  const int l   = tid & 63, wv = tid >> 6;
  const int m0  = blockIdx.x * 128;
  const int n0  = blockIdx.y * 256;
  const int TL0 = m0 >> 6;
  {
    int tv = tid >> 6, b = tid & 63;
    tokl[tv][b] = ipts[b*SLEN + t0 + TL0 + tv];
  }

  f32x4 acc[4][8];
  #pragma unroll
  for (int mt=0; mt<4; ++mt)
    #pragma unroll
    for (int nt=0; nt<8; ++nt)
      acc[mt][nt] = (f32x4){0.f,0.f,0.f,0.f};

  const int wm = wv >> 1, wn = wv & 1;
  const int lr = l & 15, lk = l >> 4;

  for (int ks = 0; ks < 12; ++ks){
    const int w0 = ks >> 2;            // conv window position (0..2)
    const int e0 = (ks & 3) << 6;      // emb col base
    __syncthreads();
    // ---- stage A: gather emb rows, convert fp32->bf16 ----
    #pragma unroll
    for (int s = 0; s < 4; ++s){
      int seg = tid + s*256;
      int row = seg >> 3, off = seg & 7;
      int tok = tokl[(row>>6) + w0][row & 63];
      const float* src = emb + (size_t)tok*NE + e0 + off*8;
      float4 f0 = *(const float4*)src;
      float4 f1 = *(const float4*)(src+4);
      unsigned int p0 = (unsigned int)f2bf(f0.x) | ((unsigned int)f2bf(f0.y)<<16);
      unsigned int p1 = (unsigned int)f2bf(f0.z) | ((unsigned int)f2bf(f0.w)<<16);
      unsigned int p2 = (unsigned int)f2bf(f1.x) | ((unsigned int)f2bf(f1.y)<<16);
      unsigned int p3 = (unsigned int)f2bf(f1.z) | ((unsigned int)f2bf(f1.w)<<16);
      *(uint4*)&A_l[row][off*8] = make_uint4(p0,p1,p2,p3);
    }
    // ---- stage B: CW2T rows n0..n0+255, cols k0..k0+63 ----
    #pragma unroll
    for (int s = 0; s < 8; ++s){
      int seg = tid + s*256;
      int row = seg >> 3, off = seg & 7;
      uint4 v = *(const uint4*)(cw2t + (size_t)(n0+row)*768 + (ks<<6) + off*8);
      *(uint4*)&B_l[row][off*8] = v;
    }
    __syncthreads();
    // ---- MFMA ----
    #pragma unroll
    for (int kf = 0; kf < 2; ++kf){
      bf16x8 af[4], bfr[8];
      #pragma unroll
      for (int mt=0; mt<4; ++mt)
        af[mt] = *(const bf16x8*)&A_l[wm*64 + mt*16 + lr][kf*32 + lk*8];
      #pragma unroll
      for (int nt=0; nt<8; ++nt)
        bfr[nt] = *(const bf16x8*)&B_l[wn*128 + nt*16 + lr][kf*32 + lk*8];
      #pragma unroll
      for (int mt=0; mt<4; ++mt)
        #pragma unroll
        for (int nt=0; nt<8; ++nt)
          acc[mt][nt] = __builtin_amdgcn_mfma_f32_16x16x32_bf16(af[mt], bfr[nt], acc[mt][nt], 0,0,0);
    }
  }

  // ---- epilogue: +bias, f16, store ----
  float bia[8];
  #pragma unroll
  for (int nt=0; nt<8; ++nt) bia[nt] = bias4[n0 + wn*128 + nt*16 + lr];
  #pragma unroll
  for (int mt=0; mt<4; ++mt){
    #pragma unroll
    for (int nt=0; nt<8; ++nt){
      #pragma unroll
      for (int r=0; r<4; ++r){
        int row = m0 + wm*64 + mt*16 + lk*4 + r;
        int col = n0 + wn*128 + nt*16 + lr;
        _Float16 hv = (_Float16)(acc[mt][nt][r] + bia[nt]);
        xh[(size_t)row*NG + col] = __builtin_bit_cast(unsigned short, hv);
      }
    }
  }
}

// LSTM chunk (round-5 config: 512 thr, wres[192] + 128 KB LDS weights).
__global__ __attribute__((amdgpu_flat_work_group_size(512,512)))
__attribute__((amdgpu_waves_per_eu(2,2)))
void k_rnn(const unsigned short* __restrict__ xh,
           const uint4* __restrict__ pall4,
           const float* __restrict__ h0,
           const float* __restrict__ c0,
           const int* __restrict__ seqlen,
           const float* __restrict__ lin_w,
           const float* __restrict__ lin_b,
           unsigned int* __restrict__ h_ws,
           float* __restrict__ c_ws,
           float* __restrict__ ms_ws,
           float* __restrict__ out,
           int t0, int tcount, int is_first, int is_last){
  __shared__ uint4 wlds4[16][512];          // 128 KB: weight pairs for cp in [0,8)
  __shared__ unsigned int hp[128];          // h as f16 pairs
  __shared__ float part2[4][2][8][68];      // [kq][jh][r][l] pitch 68
  __shared__ float red[256];
  const int b   = blockIdx.x;
  const int tid = threadIdx.x;
  const int l   = tid & 63, wv = tid >> 6;
  const int kq  = wv >> 1, jh = wv & 1;

  #pragma unroll
  for (int jj=0; jj<16; ++jj)
    wlds4[jj][tid] = pall4[(size_t)jj*512 + tid];

  unsigned int wres[192];
  #pragma unroll
  for (int j=16; j<64; ++j){
    uint4 v = pall4[(size_t)j*512 + tid];
    wres[4*(j-16)+0]=v.x; wres[4*(j-16)+1]=v.y; wres[4*(j-16)+2]=v.z; wres[4*(j-16)+3]=v.w;
  }
  #pragma unroll
  for (int i=0;i<192;++i) asm volatile("" : "+v"(wres[i]));

  float creg = 0.f, msum = 0.f;
  if (is_first){
    if (tid < 128) hp[tid] = packh2(h0[(size_t)b*NH + 2*tid], h0[(size_t)b*NH + 2*tid + 1]);
    if (tid < 256) creg = c0[(size_t)b*NH + tid];
  } else {
    if (tid < 128) hp[tid] = h_ws[b*128 + tid];
    if (tid < 256){ creg = c_ws[b*256 + tid]; msum = ms_ws[b*256 + tid]; }
  }
  const int L = seqlen[b];
  __syncthreads();

  const unsigned short* xrow = xh + (size_t)b*NG + tid;

  for (int tl=0; tl<tcount; ++tl){
    unsigned short xr0=0, xr1=0, xr2=0, xr3=0;
    if (tid < 256){
      const unsigned short* xr = xrow + (size_t)tl*NB*NG;
      xr0 = xr[0]; xr1 = xr[256]; xr2 = xr[512]; xr3 = xr[768];
    }

    float pa[8];
    #pragma unroll
    for (int r=0;r<8;++r) pa[r]=0.f;

    #pragma unroll
    for (int j=0;j<16;++j){
      uint4 v = wlds4[j][tid];
      unsigned int w4[4] = {v.x, v.y, v.z, v.w};
      #pragma unroll
      for (int e=0;e<4;++e){
        int idx = 4*j+e, cp = idx>>3, r = idx&7;
        pa[r] = dot2_acc(w4[e], hp[kq*32+cp], pa[r]);
      }
    }

    #pragma unroll
    for (int cp=8; cp<32; ++cp){
      unsigned int hpv = hp[kq*32 + cp];
      #pragma unroll
      for (int r=0;r<8;++r) pa[r] = dot2_acc(wres[(cp*8+r)-64], hpv, pa[r]);
    }

    #pragma unroll
    for (int r=0;r<8;++r) part2[kq][jh][r][l] = pa[r];
    __syncthreads();

    if (tid < 256){
      unsigned short xr4[4] = {xr0, xr1, xr2, xr3};
      float a[4];
      #pragma unroll
      for (int q=0;q<4;++q){
        int G = q*256 + tid;
        int jh2 = G>>9, rw = G&511, l2 = rw>>3, r2 = rw&7;
        float s = (float)__builtin_bit_cast(_Float16, xr4[q]);
        #pragma unroll
        for (int k=0;k<4;++k) s += part2[k][jh2][r2][l2];
        a[q] = s;
      }
      float si = sigm(a[0]), sf = sigm(a[1]), so = sigm(a[3]);
      float tg = tanh_(a[2]);
      creg = sf*creg + si*tg;
      float h2 = so*tanh_(creg);
      if (t0 + tl < L) msum += h2;
      ((_Float16*)hp)[tid] = (_Float16)h2;
    }
    __syncthreads();
  }

  if (tid < 128) h_ws[b*128 + tid] = hp[tid];
  if (tid < 256){ c_ws[b*256 + tid] = creg; ms_ws[b*256 + tid] = msum; }

  if (is_last){
    if (tid < 256) red[tid] = (msum / (float)L) * lin_w[tid];
    __syncthreads();
    if (tid < 64){
      float s = red[tid] + red[tid+64] + red[tid+128] + red[tid+192];
      #pragma unroll
      for (int off=32; off>0; off>>=1) s += __shfl_down(s, off);
      if (tid==0) out[b] = sigm(s + lin_b[0]);
    }
  }
}

extern "C" void kernel_launch(void* const* d_in, const int* in_sizes, int n_in,
                              void* d_out, int out_size, void* d_ws, size_t ws_size,
                              hipStream_t stream){
  const int*   ipts   = (const int*)d_in[0];
  const int*   seqlen = (const int*)d_in[1];
  const float* h0     = (const float*)d_in[2];
  const float* c0     = (const float*)d_in[3];
  const float* emb    = (const float*)d_in[4];
  const float* conv_w = (const float*)d_in[5];
  const float* conv_b = (const float*)d_in[6];
  const float* w_ih   = (const float*)d_in[7];
  const float* w_hh   = (const float*)d_in[8];
  const float* b_ih   = (const float*)d_in[9];
  const float* b_hh   = (const float*)d_in[10];
  const float* lin_w  = (const float*)d_in[11];
  const float* lin_b  = (const float*)d_in[12];
  float* out = (float*)d_out;

  char* ws = (char*)d_ws;
  const size_t XH_B   = (size_t)TC*NB*NG*2;      // 33.5 MB
  const size_t CW2_B  = (size_t)NG*768*2;        // 1.57 MB
  const size_t PALL_B = (size_t)64*512*16;       // 512 KB
  unsigned short* xh    = (unsigned short*)ws;
  unsigned short* cw2t  = (unsigned short*)(ws + XH_B);
  uint4*          pall4 = (uint4*)(ws + XH_B + CW2_B);
  float*          bias4 = (float*)(ws + XH_B + CW2_B + PALL_B);
  unsigned int*   h_ws  = (unsigned int*)(ws + XH_B + CW2_B + PALL_B + 4096);
  float*          c_ws  = (float*)(ws + XH_B + CW2_B + PALL_B + 4096 + 32768);
  float*          ms_ws = (float*)(ws + XH_B + CW2_B + PALL_B + 4096 + 32768 + 65536);

  k_bias<<<dim3(4),       dim3(256), 0, stream>>>(conv_b, w_ih, b_ih, b_hh, bias4);
  k_pack<<<dim3(128),     dim3(256), 0, stream>>>(w_hh, pall4);
  k_cw2 <<<dim3(12, 16),  dim3(256), 0, stream>>>(w_ih, conv_w, cw2t);

  for (int t0 = 0; t0 < TLEN; t0 += TC){
    int tcount = (TLEN - t0 < TC) ? (TLEN - t0) : TC;
    int is_first = (t0 == 0), is_last = (t0 + TC >= TLEN);
    k_fxg<<<dim3(128, 4), dim3(256), 0, stream>>>(ipts, emb, cw2t, bias4, xh, t0);
    k_rnn<<<dim3(NB),     dim3(512), 0, stream>>>(xh, pall4, h0, c0, seqlen,
                                                  lin_w, lin_b, h_ws, c_ws, ms_ws, out,
                                                  t0, tcount, is_first, is_last);
  }
}